// Round 15
// baseline (142.128 us; speedup 1.0000x reference)
//
#include <hip/hip_runtime.h>
#include <hip/hip_bf16.h>
#include <math.h>

using bf16 = __hip_bfloat16;
typedef __attribute__((ext_vector_type(8))) short bf16x8;
typedef __attribute__((ext_vector_type(8))) short short8;
typedef __attribute__((ext_vector_type(4))) float f32x4;

#define AS1 __attribute__((address_space(1)))
#define AS3 __attribute__((address_space(3)))

constexpr int BATCH = 4;
constexpr int SEQ   = 4096;
constexpr int DIM   = 2048;
constexpr int SCAN  = 128;
constexpr int STATE = 16;
constexpr int LCH   = 16;         // scan chunk length
constexpr int NCH   = SEQ / LCH;  // 256 chunks

__device__ __forceinline__ float bf2f(bf16 v) { return __bfloat162float(v); }
__device__ __forceinline__ bf16  f2bf(float v) { return __float2bfloat16(v); }
__device__ __forceinline__ float bfbits(unsigned short u) {
  return __uint_as_float((unsigned)u << 16);
}

// 256-byte-row XOR swizzle (A and B tiles in k12, tiles in k4)
__device__ __forceinline__ int swz256(int row, int colbyte) {
  return row * 256 + (colbyte ^ ((row & 7) << 4));
}

// ---------------------------------------------------------------------------
// Weights -> bf16 ws copies (Wi+Wg combined into Wzg[256][2048]); b_dt -> f32;
// A_log -> Aneg = -exp(A_log). Dtype probe inlined.
// ---------------------------------------------------------------------------
__device__ __forceinline__ int probe_dtype(const unsigned short* __restrict__ xp) {
  int cnt = 0;
  for (int i = 0; i < 512; ++i) {
    int e = (xp[i] >> 7) & 0xFF;
    cnt += (e >= 107 && e <= 147) ? 1 : 0;
  }
  return (cnt >= 410) ? 1 : 0;   // 1 = bf16, 0 = f32
}

__device__ __forceinline__ void conv_b(const void* src, bf16* dst, int n, int f,
                                       int gtid, int nt) {
  if (f) { const bf16* s = (const bf16*)src;  for (int i = gtid; i < n; i += nt) dst[i] = s[i]; }
  else   { const float* s = (const float*)src; for (int i = gtid; i < n; i += nt) dst[i] = f2bf(s[i]); }
}
__device__ __forceinline__ void conv_f(const void* src, float* dst, int n, int f,
                                       int gtid, int nt) {
  if (f) { const bf16* s = (const bf16*)src;  for (int i = gtid; i < n; i += nt) dst[i] = bf2f(s[i]); }
  else   { const float* s = (const float*)src; for (int i = gtid; i < n; i += nt) dst[i] = s[i]; }
}
__device__ __forceinline__ void conv_aneg(const void* src, float* dst, int n, int f,
                                          int gtid, int nt) {
  if (f) { const bf16* s = (const bf16*)src;  for (int i = gtid; i < n; i += nt) dst[i] = -expf(bf2f(s[i])); }
  else   { const float* s = (const float*)src; for (int i = gtid; i < n; i += nt) dst[i] = -expf(s[i]); }
}

__global__ __launch_bounds__(256) void kconv_w(
    const unsigned short* __restrict__ xprobe,
    const void* Wi, const void* Wg, const void* Wo, const void* Wdt,
    const void* Wb, const void* Wc, const void* bdt, const void* Alog,
    bf16* Wzg, bf16* Wob, bf16* Wdtb, bf16* Wbb, bf16* Wcb,
    float* bdtf, float* Anegf, int* __restrict__ flag) {
  int f = probe_dtype(xprobe);
  if (blockIdx.x == 0 && threadIdx.x == 0) *flag = f;
  int nt = gridDim.x * blockDim.x;
  int g  = blockIdx.x * blockDim.x + threadIdx.x;
  conv_b(Wi,  Wzg,               SCAN * DIM,  f, g, nt);   // rows 0..127
  conv_b(Wg,  Wzg + SCAN * DIM,  SCAN * DIM,  f, g, nt);   // rows 128..255
  conv_b(Wo,  Wob,  DIM * SCAN,  f, g, nt);
  conv_b(Wdt, Wdtb, SCAN * SCAN, f, g, nt);
  conv_b(Wb,  Wbb,  STATE * SCAN, f, g, nt);
  conv_b(Wc,  Wcb,  STATE * SCAN, f, g, nt);
  conv_f(bdt,  bdtf,  SCAN,          f, g, nt);
  conv_aneg(Alog, Anegf, SCAN * STATE, f, g, nt);
}

// ---------------------------------------------------------------------------
// K12 (1024 threads = 16 waves = 4 waves/SIMD), BK=128, depth-2, 160 KiB LDS:
//   per iter (16 total): issue stage(t+1) -> compute(t) [16 MFMA/wave]
//                        -> vmcnt(0) -> writeA(t+1) -> lgkm0+barrier
//   phase 2-4 tail unchanged (aliases buffer LDS).
// ---------------------------------------------------------------------------
struct ARegs { float4 v[2]; };   // f32: 8 floats; bf16: 8 bf16 in v[0]

template <int F>
__device__ __forceinline__ ARegs loadA(const void* __restrict__ xin, size_t rowbase,
                                       int k0, int ae) {
  ARegs r;
  if (F) {   // bf16: 8 elems = 16 B
    r.v[0] = *(const float4*)((const bf16*)xin + rowbase + k0 + ae);
  } else {   // f32: 8 elems = 32 B
    const float4* s = (const float4*)((const float*)xin + rowbase + k0 + ae);
    r.v[0] = s[0]; r.v[1] = s[1];
  }
  return r;
}

template <int F>
__device__ __forceinline__ void writeA(char* abuf, int ar, int ae, const ARegs& rg) {
  char* d = abuf + swz256(ar, ae * 2);   // 16-B write; XOR bits 4-6 keep alignment
  if (F) {
    *(float4*)d = rg.v[0];
  } else {
    union { short8 s; bf16 b[8]; } u;
    const float* fv = (const float*)&rg.v[0];
#pragma unroll
    for (int i = 0; i < 8; ++i) u.b[i] = f2bf(fv[i]);
    *(short8*)d = u.s;
  }
}

// B tile 256x128 bf16 = 64 KB (256 B/row); 1024 thr x 16B x 4 issues;
// pre-swizzled global source, linear LDS dest.
__device__ __forceinline__ void stageB(const bf16* __restrict__ W, int k0,
                                       char* bbuf, int tid) {
  int w = tid >> 6;
#pragma unroll
  for (int i = 0; i < 4; ++i) {
    int off = i * 16384 + tid * 16;      // linear LDS byte offset
    int r   = off >> 8;                  // row (256 B per row)
    int cbl = off & 255;
    int cbs = cbl ^ ((r & 7) << 4);      // inverse-swizzled source col byte
    const bf16* src = W + (size_t)r * DIM + k0 + (cbs >> 1);
    char* lb = bbuf + i * 16384 + w * 1024;  // wave-uniform base; HW adds lane*16
    __builtin_amdgcn_global_load_lds((const AS1 void*)src, (AS3 void*)lb, 16, 0, 0);
  }
}

__device__ __forceinline__ void compute64x256_k128(const char* abuf, const char* bbuf,
                                                   int tid, f32x4 acc[2][2]) {
  int l = tid & 63, w = tid >> 6;
  int wr = (w >> 3) * 32;            // row group 0 or 32
  int wc = (w & 7) * 32;             // col group 0..224
  int lr = l & 15, lk = (l >> 4) * 8;
#pragma unroll
  for (int kk = 0; kk < 128; kk += 32) {
    int cb = (kk + lk) * 2;
    bf16x8 a[2], b[2];
#pragma unroll
    for (int m = 0; m < 2; ++m)
      a[m] = *(const bf16x8*)(abuf + swz256(wr + m * 16 + lr, cb));
#pragma unroll
    for (int n = 0; n < 2; ++n)
      b[n] = *(const bf16x8*)(bbuf + swz256(wc + n * 16 + lr, cb));
#pragma unroll
    for (int m = 0; m < 2; ++m)
#pragma unroll
      for (int n = 0; n < 2; ++n)
        acc[m][n] = __builtin_amdgcn_mfma_f32_16x16x32_bf16(a[m], b[n], acc[m][n], 0, 0, 0);
  }
}

__device__ __forceinline__ void vm_wait0() { asm volatile("s_waitcnt vmcnt(0)" ::: "memory"); __builtin_amdgcn_sched_barrier(0); }
__device__ __forceinline__ void lgkm0_barrier() {
  asm volatile("s_waitcnt lgkmcnt(0)" ::: "memory");
  __builtin_amdgcn_sched_barrier(0);
  __builtin_amdgcn_s_barrier();
}

template <int F>
__device__ __forceinline__ void k1_main(const void* __restrict__ xin,
                                        const bf16* __restrict__ W,
                                        char* lds, size_t xrow, int ar, int ae,
                                        int tid, f32x4 acc[2][2]) {
  constexpr int NK  = DIM / 128;   // 16
  constexpr int BUF = 81920;       // 16K A + 64K B
  {
    ARegs a0 = loadA<F>(xin, xrow, 0, ae);
    stageB(W, 0, lds + 16384, tid);
    vm_wait0();
    writeA<F>(lds, ar, ae, a0);
    lgkm0_barrier();
  }
  for (int t = 0; t < NK; ++t) {
    char* cur = lds + (t & 1) * BUF;
    char* nxt = lds + ((t + 1) & 1) * BUF;
    ARegs aN;
    if (t + 1 < NK) {
      aN = loadA<F>(xin, xrow, (t + 1) * 128, ae);
      stageB(W, (t + 1) * 128, nxt + 16384, tid);   // lands under compute
    }
    compute64x256_k128(cur, cur + 16384, tid, acc);
    if (t + 1 < NK) {
      vm_wait0();
      writeA<F>(nxt, ar, ae, aN);
      lgkm0_barrier();
    }
  }
}

__global__ __launch_bounds__(1024) void k12_zg(const void* __restrict__ xin,
                                               const bf16* __restrict__ Wzg,
                                               const bf16* __restrict__ Wdtb,
                                               const bf16* __restrict__ Wbb,
                                               const bf16* __restrict__ Wcb,
                                               const float* __restrict__ bdtf,
                                               const float* __restrict__ Aneg,
                                               bf16* __restrict__ z,
                                               bf16* __restrict__ gate,
                                               float* __restrict__ dt,
                                               float* __restrict__ Bv,
                                               float* __restrict__ Cv,
                                               float* __restrict__ fin,
                                               float* __restrict__ apr,
                                               const int* __restrict__ flag) {
  __shared__ char lds[163840];         // 2 x (16K A + 64K B) = full 160 KiB
  int tid = threadIdx.x;               // 0..1023
  int mb  = blockIdx.x;
  int m0  = mb * 64;
  int f   = *flag;
  int ar  = tid >> 4;                  // A row 0..63
  int ae  = (tid & 15) * 8;            // A col (elems), 8/thread
  size_t xrow = ((size_t)m0 + ar) * DIM;

  f32x4 acc[2][2];
#pragma unroll
  for (int m = 0; m < 2; ++m)
#pragma unroll
    for (int n = 0; n < 2; ++n)
#pragma unroll
      for (int j = 0; j < 4; ++j) acc[m][n][j] = 0.f;

  if (f) k1_main<1>(xin, Wzg, lds, xrow, ar, ae, tid, acc);
  else   k1_main<0>(xin, Wzg, lds, xrow, ar, ae, tid, acc);

  __syncthreads();   // all waves past last compute; LDS free for reuse

  // ----- phase 2: epilogue -> global z/gate, z into LDS -----
  bf16 (*zl)[128]   = (bf16 (*)[128])(lds);           // 16384 B
  bf16 (*wl)[136]   = (bf16 (*)[136])(lds + 16384);   // 43520 -> 59904
  bf16 (*dtlb)[128] = (bf16 (*)[128])(lds + 59904);   // 16384 -> 76288
  bf16 (*Blcb)[16]  = (bf16 (*)[16]) (lds + 76288);   //  2048 -> 78336

  {
    int l = tid & 63, w = tid >> 6;
    int wr = (w >> 3) * 32;
    int wcg = (w & 7) * 32;            // global output col base 0..224
    int sel = wcg >> 7;                // 0 -> z, 1 -> gate
    int cb  = wcg & 127;
    int lr = l & 15, lj = (l >> 4) * 4;
    bf16* o = sel ? gate : z;
#pragma unroll
    for (int m = 0; m < 2; ++m)
#pragma unroll
      for (int n = 0; n < 2; ++n)
#pragma unroll
        for (int j = 0; j < 4; ++j) {
          int rowl = wr + m * 16 + lj + j;
          int col  = cb + n * 16 + lr;
          float v = acc[m][n][j];
          if (sel) v = v / (1.f + expf(-v));   // silu
          bf16 bv = f2bf(v);
          o[(size_t)(m0 + rowl) * SCAN + col] = bv;
          if (!sel) zl[rowl][col] = bv;
        }
  }
  // stage small-GEMM weights (L2-resident, plain vector loads; 1024 threads)
  for (int idx = tid; idx < 160 * 16; idx += 1024) {
    int r = idx >> 4, c8 = (idx & 15) << 3;
    const bf16* src;
    if (r < 128)      src = Wdtb + r * 128;
    else if (r < 144) src = Wbb + (r - 128) * 128;
    else              src = Wcb + (r - 144) * 128;
    *(short8*)&wl[r][c8] = *(const short8*)(src + c8);
  }
  __syncthreads();

  // ----- phase 3: dt/Bv/Cv GEMM (waves 0-3 only) -----
  if (tid < 256) {
    int l = tid & 63, w = tid >> 6;
    int lr = l & 15, lk = (l >> 4) * 8, lj = (l >> 4) * 4;
    f32x4 acc2[10];
#pragma unroll
    for (int n = 0; n < 10; ++n)
#pragma unroll
      for (int j = 0; j < 4; ++j) acc2[n][j] = 0.f;

#pragma unroll
    for (int kk = 0; kk < 128; kk += 32) {
      bf16x8 a = *(const bf16x8*)&zl[w * 16 + lr][kk + lk];
#pragma unroll
      for (int n = 0; n < 10; ++n) {
        bf16x8 bfr = *(const bf16x8*)&wl[n * 16 + lr][kk + lk];
        acc2[n] = __builtin_amdgcn_mfma_f32_16x16x32_bf16(a, bfr, acc2[n], 0, 0, 0);
      }
    }

#pragma unroll
    for (int n = 0; n < 10; ++n) {
      int o = n * 16 + lr;
#pragma unroll
      for (int j = 0; j < 4; ++j) {
        int row = w * 16 + lj + j;          // local row 0..63
        float v = acc2[n][j];
        if (o < 128) {
          v += bdtf[o];
          v = fmaxf(v, 0.f) + log1pf(expf(-fabsf(v)));   // stable softplus
          dt[(size_t)(m0 + row) * SCAN + o] = v;
          dtlb[row][o] = f2bf(v);
        } else if (o < 144) {
          Bv[(size_t)(m0 + row) * STATE + (o - 128)] = v;
          Blcb[row][o - 128] = f2bf(v);
        } else {
          Cv[(size_t)(m0 + row) * STATE + (o - 144)] = v;
        }
      }
    }
  }
  __syncthreads();

  // ----- phase 4: local scan, threads < 512 = (chunk 0..3) x (n 0..127) -----
  if (tid < 512) {
    int n  = tid & 127;
    int cc = tid >> 7;                       // chunk 0..3
    int b   = m0 >> 12;
    int ch0 = (m0 & 4095) >> 4;
    float A[STATE];
#pragma unroll
    for (int k = 0; k < STATE; ++k) A[k] = Aneg[n * STATE + k];

    float st[STATE], ap[STATE];
#pragma unroll
    for (int k = 0; k < STATE; ++k) { st[k] = 0.f; ap[k] = 1.f; }
#pragma unroll
    for (int t = 0; t < LCH; ++t) {
      int row = cc * LCH + t;
      float d = bf2f(dtlb[row][n]);
      float u = d * bf2f(zl[row][n]);
#pragma unroll
      for (int kg = 0; kg < 4; ++kg) {
        unsigned long long bb = *(const unsigned long long*)&Blcb[row][kg * 4];
        float b0 = bfbits((unsigned short)bb);
        float b1 = bfbits((unsigned short)(bb >> 16));
        float b2 = bfbits((unsigned short)(bb >> 32));
        float b3 = bfbits((unsigned short)(bb >> 48));
        float a;
        a = fmaf(d, A[kg*4+0], 1.f); st[kg*4+0] = fmaf(a, st[kg*4+0], u * b0); ap[kg*4+0] *= a;
        a = fmaf(d, A[kg*4+1], 1.f); st[kg*4+1] = fmaf(a, st[kg*4+1], u * b1); ap[kg*4+1] *= a;
        a = fmaf(d, A[kg*4+2], 1.f); st[kg*4+2] = fmaf(a, st[kg*4+2], u * b2); ap[kg*4+2] *= a;
        a = fmaf(d, A[kg*4+3], 1.f); st[kg*4+3] = fmaf(a, st[kg*4+3], u * b3); ap[kg*4+3] *= a;
      }
    }
    size_t base = ((size_t)b * NCH + (ch0 + cc)) * (STATE * SCAN) + n;
#pragma unroll
    for (int k = 0; k < STATE; ++k) {
      fin[base + k * SCAN] = st[k];
      apr[base + k * SCAN] = ap[k];
    }
  }
}

// ---------------------------------------------------------------------------
// K3b: combine across chunks; apr overwritten in place with INCOMING state.
// ---------------------------------------------------------------------------
__global__ __launch_bounds__(64) void k3b(const float* __restrict__ fin,
                                          float* __restrict__ apr) {
  int c  = blockIdx.x * 64 + threadIdx.x;   // 0..8191
  int b  = c >> 11;
  int kn = c & 2047;
  size_t base = (size_t)b * NCH * 2048 + kn;
  float s = 0.f;
  for (int g = 0; g < NCH; g += 16) {
    float fv[16], av[16];
#pragma unroll
    for (int i = 0; i < 16; ++i) {
      size_t o = base + (size_t)(g + i) * 2048;
      fv[i] = fin[o];
      av[i] = apr[o];
    }
#pragma unroll
    for (int i = 0; i < 16; ++i) {
      size_t o = base + (size_t)(g + i) * 2048;
      apr[o] = s;
      s = fmaf(av[i], s, fv[i]);
    }
  }
}

// ---------------------------------------------------------------------------
// K3c: re-scan with incoming state; yg = (sum_k st*C) * gate (bf16).
// yg aliases z (each element read before written by the same thread).
// ---------------------------------------------------------------------------
__global__ __launch_bounds__(128) void k3c(
    const float* __restrict__ dt, const bf16* z,
    const float* __restrict__ Bv, const float* __restrict__ Cv,
    const float* __restrict__ Aneg, const float* __restrict__ inc,
    const bf16* __restrict__ gate, bf16* yg) {
  __shared__ float Bl[LCH][STATE];
  __shared__ float Cl[LCH][STATE];
  int n  = threadIdx.x;
  int ch = blockIdx.x, b = blockIdx.y;
  int t0 = ch * LCH;
  if (n < LCH * STATE / 4)
    ((float4*)&Bl[0][0])[n] = ((const float4*)(Bv + ((size_t)b * SEQ + t0) * STATE))[n];
  else if (n < LCH * STATE / 2)
    ((float4*)&Cl[0][0])[n - LCH * STATE / 4] =
        ((const float4*)(Cv + ((size_t)b * SEQ + t0) * STATE))[n - LCH * STATE / 4];

  size_t base = ((size_t)b * NCH + ch) * (STATE * SCAN) + n;
  float A[STATE], st[STATE];
#pragma unroll
  for (int k = 0; k < STATE; ++k) {
    A[k]  = Aneg[n * STATE + k];
    st[k] = inc[base + k * SCAN];
  }
  __syncthreads();

  const float* dtp = dt   + ((size_t)b * SEQ + t0) * SCAN + n;
  const bf16*  zp  = z    + ((size_t)b * SEQ + t0) * SCAN + n;
  const bf16*  gp  = gate + ((size_t)b * SEQ + t0) * SCAN + n;
  bf16*        yp  = yg   + ((size_t)b * SEQ + t0) * SCAN + n;
#pragma unroll 4
  for (int t = 0; t < LCH; ++t) {
    float d = dtp[t * SCAN];
    float u = d * bf2f(zp[t * SCAN]);
    float g = bf2f(gp[t * SCAN]);
    float y0 = 0.f, y1 = 0.f, y2 = 0.f, y3 = 0.f;
#pragma unroll
    for (int kg = 0; kg < 4; ++kg) {
      float4 B4 = *(const float4*)&Bl[t][kg * 4];
      float4 C4 = *(const float4*)&Cl[t][kg * 4];
      float a, p = 0.f;
      a = fmaf(d, A[kg*4+0], 1.f); st[kg*4+0] = fmaf(a, st[kg*4+0], u * B4.x); p = fmaf(st[kg*4+0], C4.x, p);
      a = fmaf(d, A[kg*4+1], 1.f); st[kg*4+1] = fmaf(a, st[kg*4+1], u * B4.y); p = fmaf(st[kg*4+1], C4.y, p);
      a = fmaf(d, A[kg*4+2], 1.f); st[kg*4+2] = fmaf(a, st[kg*4+2], u * B4.z); p = fmaf(st[kg*4+2], C4.z, p);
      a = fmaf(d, A[kg*4+3], 1.f); st[kg*4+3] = fmaf(a, st[kg*4+3], u * B4.w); p = fmaf(st[kg*4+3], C4.w, p);
      if (kg == 0) y0 = p; else if (kg == 1) y1 = p; else if (kg == 2) y2 = p; else y3 = p;
    }
    float y = (y0 + y1) + (y2 + y3);
    yp[t * SCAN] = f2bf(y * g);
  }
}

// ---------------------------------------------------------------------------
// K4: out = yg @ Wo^T -> [16384,2048]. BM=128, BN=64, K=128 staged whole
// (48 KB, single barrier, XOR-swizzled). grid(128,32), 3 blocks/CU.
// ---------------------------------------------------------------------------
__global__ __launch_bounds__(256) void k4_out(const bf16* __restrict__ yg,
                                              const bf16* __restrict__ Wo,
                                              void* __restrict__ outv,
                                              const int* __restrict__ flag) {
  __shared__ char lds[49152];   // A 32K @0, B 16K @32768
  int tid = threadIdx.x;
  int mb = blockIdx.x, nb = blockIdx.y;
  int w = tid >> 6;

#pragma unroll
  for (int i = 0; i < 8; ++i) {
    int off = i * 4096 + tid * 16;
    int r   = off >> 8;
    int cbl = off & 255;
    int cbs = cbl ^ ((r & 7) << 4);
    const bf16* src = yg + (size_t)(mb * 128 + r) * SCAN + (cbs >> 1);
    __builtin_amdgcn_global_load_lds((const AS1 void*)src,
                                     (AS3 void*)(lds + i * 4096 + w * 1024), 16, 0, 0);
  }
#pragma unroll
  for (int i = 0; i < 4; ++i) {
    int off = i * 4096 + tid * 16;
    int r   = off >> 8;
    int cbl = off & 255;
    int cbs = cbl ^ ((r & 7) << 4);
    const bf16* src = Wo + (size_t)(nb * 64 + r) * SCAN + (cbs >> 1);
    __builtin_amdgcn_global_load_lds((const AS1 void*)src,
                                     (AS3 void*)(lds + 32768 + i * 4096 + w * 1024), 16, 0, 0);
  }
  __syncthreads();

  int l = tid & 63;
  int lr = l & 15, lk = (l >> 4) * 8;
  f32x4 acc[2][4];
#pragma unroll
  for (int m = 0; m < 2; ++m)
#pragma unroll
    for (int n = 0; n < 4; ++n)
#pragma unroll
      for (int j = 0; j < 4; ++j) acc[m][n][j] = 0.f;

#pragma unroll
  for (int kk = 0; kk < 128; kk += 32) {
    int cb = (kk + lk) * 2;
    bf16x8 a[2], b[4];
#pragma unroll
    for (int m = 0; m < 2; ++m)
      a[m] = *(const bf16x8*)(lds + swz256(w * 32 + m * 16 + lr, cb));
#pragma unroll
    for (int n = 0; n < 4; ++n)
      b[n] = *(const bf16x8*)(lds + 32768 + swz256(n * 16 + lr, cb));
#pragma unroll
    for (int m = 0; m < 2; ++m)
#pragma unroll
      for (int n = 0; n < 4; ++n)
        acc[m][n] = __builtin_amdgcn_mfma_f32_16x16x32_bf16(a[m], b[n], acc[m][n], 0, 0, 0);
  }

  int f = *flag;
  int lj = (l >> 4) * 4;
#pragma unroll
  for (int m = 0; m < 2; ++m)
#pragma unroll
    for (int n = 0; n < 4; ++n)
#pragma unroll
      for (int j = 0; j < 4; ++j) {
        int row = mb * 128 + w * 32 + m * 16 + lj + j;
        int col = nb * 64 + n * 16 + lr;
        size_t off = (size_t)row * DIM + col;
        float v = acc[m][n][j];
        if (f) ((bf16*)outv)[off] = f2bf(v);
        else   ((float*)outv)[off] = v;
      }
}

// ---------------------------------------------------------------------------
extern "C" void kernel_launch(void* const* d_in, const int* in_sizes, int n_in,
                              void* d_out, int out_size, void* d_ws, size_t ws_size,
                              hipStream_t stream) {
  const void* x     = d_in[0];
  const void* Wi    = d_in[1];
  const void* Wo    = d_in[2];
  const void* A_log = d_in[3];
  const void* Wb    = d_in[4];
  const void* Wc    = d_in[5];
  const void* Wdt   = d_in[6];
  const void* b_dt  = d_in[7];
  const void* Wg    = d_in[8];

  const size_t M = (size_t)BATCH * SEQ;   // 16384
  char* p = (char*)d_ws;
  int*   flag = (int*)p;    p += 256;
  bf16*  Wzg  = (bf16*)p;   p += (size_t)2 * SCAN * DIM * 2;   // [256][2048]
  bf16*  Wob  = (bf16*)p;   p += (size_t)DIM * SCAN * 2;
  bf16*  Wdtb = (bf16*)p;   p += (size_t)SCAN * SCAN * 2;
  bf16*  Wbb  = (bf16*)p;   p += (size_t)STATE * SCAN * 2;
  bf16*  Wcb  = (bf16*)p;   p += (size_t)STATE * SCAN * 2;
  float* bdtf = (float*)p;  p += SCAN * 4;
  float* Anegf= (float*)p;  p += (size_t)SCAN * STATE * 4;
  bf16*  z    = (bf16*)p;   p += M * SCAN * 2;
  bf16*  gate = (bf16*)p;   p += M * SCAN * 2;
  bf16*  yg   = z;                                   // alias: k3c reads z before writing yg
  float* dt   = (float*)p;  p += M * SCAN * 4;
  float* Bv   = (float*)p;  p += M * STATE * 4;
  float* Cv   = (float*)p;  p += M * STATE * 4;
  float* fin  = (float*)p;  p += (size_t)BATCH * NCH * SCAN * STATE * 4;
  float* apr  = (float*)p;  p += (size_t)BATCH * NCH * SCAN * STATE * 4;   // becomes inc after k3b

  kconv_w <<<256, 256, 0, stream>>>((const unsigned short*)x,
                                    Wi, Wg, Wo, Wdt, Wb, Wc, b_dt, A_log,
                                    Wzg, Wob, Wdtb, Wbb, Wcb, bdtf, Anegf, flag);
  k12_zg  <<<dim3(256), 1024, 0, stream>>>(x, Wzg, Wdtb, Wbb, Wcb, bdtf, Anegf,
                                           z, gate, dt, Bv, Cv, fin, apr, flag);
  k3b     <<<dim3(128), 64, 0, stream>>>(fin, apr);
  k3c     <<<dim3(NCH, BATCH), 128, 0, stream>>>(dt, z, Bv, Cv, Anegf, apr, gate, yg);
  k4_out  <<<dim3(128, 32), 256, 0, stream>>>(yg, Wob, d_out, flag);
}

// Round 16
// 129.481 us; speedup vs baseline: 1.0977x; 1.0977x over previous
//
#include <hip/hip_runtime.h>
#include <hip/hip_bf16.h>
#include <math.h>

using bf16 = __hip_bfloat16;
typedef __attribute__((ext_vector_type(8))) short bf16x8;
typedef __attribute__((ext_vector_type(8))) short short8;
typedef __attribute__((ext_vector_type(4))) float f32x4;

#define AS1 __attribute__((address_space(1)))
#define AS3 __attribute__((address_space(3)))

constexpr int BATCH = 4;
constexpr int SEQ   = 4096;
constexpr int DIM   = 2048;
constexpr int SCAN  = 128;
constexpr int STATE = 16;
constexpr int LCH   = 16;         // scan chunk length
constexpr int NCH   = SEQ / LCH;  // 256 chunks

__device__ __forceinline__ float bf2f(bf16 v) { return __bfloat162float(v); }
__device__ __forceinline__ bf16  f2bf(float v) { return __float2bfloat16(v); }
__device__ __forceinline__ float bfbits(unsigned short u) {
  return __uint_as_float((unsigned)u << 16);
}

// ---------------------------------------------------------------------------
// Weights -> bf16 ws copies (Wi+Wg combined into Wzg[256][2048]); b_dt -> f32;
// A_log -> Aneg = -exp(A_log). Dtype probe: 64 samples (f32-as-u16 alternates
// random-mantissa low halves ~16% in-range with exp halves ~100% -> ~58%;
// true bf16 ~100%; threshold 51/64 = 80%).
// ---------------------------------------------------------------------------
__device__ __forceinline__ int probe_dtype(const unsigned short* __restrict__ xp) {
  int cnt = 0;
#pragma unroll
  for (int i = 0; i < 64; ++i) {
    int e = (xp[i] >> 7) & 0xFF;
    cnt += (e >= 107 && e <= 147) ? 1 : 0;
  }
  return (cnt >= 51) ? 1 : 0;   // 1 = bf16, 0 = f32
}

__device__ __forceinline__ void conv_b(const void* src, bf16* dst, int n, int f,
                                       int gtid, int nt) {
  if (f) { const bf16* s = (const bf16*)src;  for (int i = gtid; i < n; i += nt) dst[i] = s[i]; }
  else   { const float* s = (const float*)src; for (int i = gtid; i < n; i += nt) dst[i] = f2bf(s[i]); }
}
__device__ __forceinline__ void conv_f(const void* src, float* dst, int n, int f,
                                       int gtid, int nt) {
  if (f) { const bf16* s = (const bf16*)src;  for (int i = gtid; i < n; i += nt) dst[i] = bf2f(s[i]); }
  else   { const float* s = (const float*)src; for (int i = gtid; i < n; i += nt) dst[i] = s[i]; }
}
__device__ __forceinline__ void conv_aneg(const void* src, float* dst, int n, int f,
                                          int gtid, int nt) {
  if (f) { const bf16* s = (const bf16*)src;  for (int i = gtid; i < n; i += nt) dst[i] = -expf(bf2f(s[i])); }
  else   { const float* s = (const float*)src; for (int i = gtid; i < n; i += nt) dst[i] = -expf(s[i]); }
}

__global__ __launch_bounds__(256) void kconv_w(
    const unsigned short* __restrict__ xprobe,
    const void* Wi, const void* Wg, const void* Wo, const void* Wdt,
    const void* Wb, const void* Wc, const void* bdt, const void* Alog,
    bf16* Wzg, bf16* Wob, bf16* Wdtb, bf16* Wbb, bf16* Wcb,
    float* bdtf, float* Anegf, int* __restrict__ flag) {
  int f = probe_dtype(xprobe);
  if (blockIdx.x == 0 && threadIdx.x == 0) *flag = f;
  int nt = gridDim.x * blockDim.x;
  int g  = blockIdx.x * blockDim.x + threadIdx.x;
  conv_b(Wi,  Wzg,               SCAN * DIM,  f, g, nt);   // rows 0..127
  conv_b(Wg,  Wzg + SCAN * DIM,  SCAN * DIM,  f, g, nt);   // rows 128..255
  conv_b(Wo,  Wob,  DIM * SCAN,  f, g, nt);
  conv_b(Wdt, Wdtb, SCAN * SCAN, f, g, nt);
  conv_b(Wb,  Wbb,  STATE * SCAN, f, g, nt);
  conv_b(Wc,  Wcb,  STATE * SCAN, f, g, nt);
  conv_f(bdt,  bdtf,  SCAN,          f, g, nt);
  conv_aneg(Alog, Anegf, SCAN * STATE, f, g, nt);
}

// ---------------------------------------------------------------------------
// K12 (1024 threads = 16 waves = 4 waves/SIMD), BK=64, depth-3 counted-vmcnt
// (r14 config, best measured). Per 64-row block:
//   phase 1: z|gate = x @ [Wi;Wg]^T
//   phase 2: epilogue -> z/gate global + z into LDS
//   phase 3: dt/Bv/Cv small GEMM (waves 0-3)
//   phase 4: local chunk scan (threads < 512)
// ---------------------------------------------------------------------------
__device__ __forceinline__ int swzb(int row, int colbyte) {
  return row * 128 + (colbyte ^ ((row & 7) << 4));
}

struct ARegs { float4 v; };   // f32: 4 floats; bf16: 4 bf16 in v.x/v.y

template <int F>
__device__ __forceinline__ ARegs loadA(const void* __restrict__ xin, size_t rowbase,
                                       int k0, int ae) {
  ARegs r;
  if (F) {   // bf16: 4 elems = 8 B
    float2 t = *(const float2*)((const bf16*)xin + rowbase + k0 + ae);
    r.v.x = t.x; r.v.y = t.y; r.v.z = 0.f; r.v.w = 0.f;
  } else {   // f32: 4 elems = 16 B
    r.v = *(const float4*)((const float*)xin + rowbase + k0 + ae);
  }
  return r;
}

template <int F>
__device__ __forceinline__ void writeA(char* abuf, int ar, int ae, const ARegs& rg) {
  char* d = abuf + swzb(ar, ae * 2);    // 8-byte write; XOR bits are 4-6, safe
  if (F) {
    *(float2*)d = make_float2(rg.v.x, rg.v.y);
  } else {
    union { float2 f2; bf16 b[4]; } u;
    u.b[0] = f2bf(rg.v.x); u.b[1] = f2bf(rg.v.y);
    u.b[2] = f2bf(rg.v.z); u.b[3] = f2bf(rg.v.w);
    *(float2*)d = u.f2;
  }
}

// B tile 256x64 bf16 = 32 KB; 1024 thr x 16B x 2 issues; pre-swizzled source.
__device__ __forceinline__ void stageB(const bf16* __restrict__ W, int k0,
                                       char* bbuf, int tid) {
  int w = tid >> 6;
#pragma unroll
  for (int i = 0; i < 2; ++i) {
    int off = i * 16384 + tid * 16;      // linear LDS byte offset
    int r   = off >> 7;                  // row (128 B per row)
    int cbl = off & 127;
    int cbs = cbl ^ ((r & 7) << 4);      // inverse-swizzled source col byte
    const bf16* src = W + (size_t)r * DIM + k0 + (cbs >> 1);
    char* lb = bbuf + i * 16384 + w * 1024;  // wave-uniform base; HW adds lane*16
    __builtin_amdgcn_global_load_lds((const AS1 void*)src, (AS3 void*)lb, 16, 0, 0);
  }
}

__device__ __forceinline__ void compute64x256_16w(const char* abuf, const char* bbuf,
                                                  int tid, f32x4 acc[2][2]) {
  int l = tid & 63, w = tid >> 6;
  int wr = (w >> 3) * 32;            // row group 0 or 32
  int wc = (w & 7) * 32;             // col group 0..224
  int lr = l & 15, lk = (l >> 4) * 8;
#pragma unroll
  for (int kk = 0; kk < 64; kk += 32) {
    int cb = (kk + lk) * 2;
    bf16x8 a[2], b[2];
#pragma unroll
    for (int m = 0; m < 2; ++m)
      a[m] = *(const bf16x8*)(abuf + swzb(wr + m * 16 + lr, cb));
#pragma unroll
    for (int n = 0; n < 2; ++n)
      b[n] = *(const bf16x8*)(bbuf + swzb(wc + n * 16 + lr, cb));
#pragma unroll
    for (int m = 0; m < 2; ++m)
#pragma unroll
      for (int n = 0; n < 2; ++n)
        acc[m][n] = __builtin_amdgcn_mfma_f32_16x16x32_bf16(a[m], b[n], acc[m][n], 0, 0, 0);
  }
}

__device__ __forceinline__ void vm_wait3() { asm volatile("s_waitcnt vmcnt(3)" ::: "memory"); __builtin_amdgcn_sched_barrier(0); }
__device__ __forceinline__ void vm_wait0() { asm volatile("s_waitcnt vmcnt(0)" ::: "memory"); __builtin_amdgcn_sched_barrier(0); }
__device__ __forceinline__ void lgkm0_barrier() {
  asm volatile("s_waitcnt lgkmcnt(0)" ::: "memory");
  __builtin_amdgcn_sched_barrier(0);
  __builtin_amdgcn_s_barrier();
}

template <int F>
__device__ __forceinline__ void k1_main(const void* __restrict__ xin,
                                        const bf16* __restrict__ W,
                                        char* lds, size_t xrow, int ar, int ae,
                                        int tid, f32x4 acc[2][2]) {
  constexpr int NK = DIM / 64;   // 32
  constexpr int BUF = 40960;     // 8K A + 32K B
  ARegs aH = loadA<F>(xin, xrow, 0, ae);
  stageB(W, 0, lds + 0 * BUF + 8192, tid);
  ARegs aN = loadA<F>(xin, xrow, 64, ae);
  stageB(W, 64, lds + 1 * BUF + 8192, tid);
  vm_wait3();                    // stage0 complete; stage1's 3 in flight
  writeA<F>(lds + 0 * BUF, ar, ae, aH);
  aH = aN;
  lgkm0_barrier();

  for (int t = 0; t < NK; ++t) {
    char* curb = lds + (t % 3) * BUF;
    if (t + 2 < NK) {
      aN = loadA<F>(xin, xrow, (t + 2) * 64, ae);
      stageB(W, (t + 2) * 64, lds + ((t + 2) % 3) * BUF + 8192, tid);
    }
    compute64x256_16w(curb, curb + 8192, tid, acc);
    if (t + 1 < NK) {
      if (t + 2 < NK) vm_wait3();
      else            vm_wait0();
      writeA<F>(lds + ((t + 1) % 3) * BUF, ar, ae, aH);
      aH = aN;
      lgkm0_barrier();
    }
  }
}

__global__ __launch_bounds__(1024) void k12_zg(const void* __restrict__ xin,
                                               const bf16* __restrict__ Wzg,
                                               const bf16* __restrict__ Wdtb,
                                               const bf16* __restrict__ Wbb,
                                               const bf16* __restrict__ Wcb,
                                               const float* __restrict__ bdtf,
                                               const float* __restrict__ Aneg,
                                               bf16* __restrict__ z,
                                               bf16* __restrict__ gate,
                                               float* __restrict__ dt,
                                               float* __restrict__ Bv,
                                               float* __restrict__ Cv,
                                               float* __restrict__ fin,
                                               float* __restrict__ apr,
                                               const int* __restrict__ flag) {
  __shared__ char lds[122880];
  int tid = threadIdx.x;               // 0..1023
  int mb  = blockIdx.x;
  int m0  = mb * 64;
  int f   = *flag;
  int ar  = tid >> 4;                  // A row 0..63
  int ae  = (tid & 15) * 4;            // A col (elems), 4/thread
  size_t xrow = ((size_t)m0 + ar) * DIM;

  f32x4 acc[2][2];
#pragma unroll
  for (int m = 0; m < 2; ++m)
#pragma unroll
    for (int n = 0; n < 2; ++n)
#pragma unroll
      for (int j = 0; j < 4; ++j) acc[m][n][j] = 0.f;

  if (f) k1_main<1>(xin, Wzg, lds, xrow, ar, ae, tid, acc);
  else   k1_main<0>(xin, Wzg, lds, xrow, ar, ae, tid, acc);

  __syncthreads();   // all waves past last compute; LDS free for reuse

  // ----- phase 2: epilogue -> global z/gate, z into LDS -----
  bf16 (*zl)[128]   = (bf16 (*)[128])(lds);           // 16384 B
  bf16 (*wl)[136]   = (bf16 (*)[136])(lds + 16384);   // 43520 -> 59904
  bf16 (*dtlb)[128] = (bf16 (*)[128])(lds + 59904);   // 16384 -> 76288
  bf16 (*Blcb)[16]  = (bf16 (*)[16]) (lds + 76288);   //  2048 -> 78336

  {
    int l = tid & 63, w = tid >> 6;
    int wr = (w >> 3) * 32;
    int wcg = (w & 7) * 32;            // global output col base 0..224
    int sel = wcg >> 7;                // 0 -> z, 1 -> gate
    int cb  = wcg & 127;
    int lr = l & 15, lj = (l >> 4) * 4;
    bf16* o = sel ? gate : z;
#pragma unroll
    for (int m = 0; m < 2; ++m)
#pragma unroll
      for (int n = 0; n < 2; ++n)
#pragma unroll
        for (int j = 0; j < 4; ++j) {
          int rowl = wr + m * 16 + lj + j;
          int col  = cb + n * 16 + lr;
          float v = acc[m][n][j];
          if (sel) v = v / (1.f + expf(-v));   // silu
          bf16 bv = f2bf(v);
          o[(size_t)(m0 + rowl) * SCAN + col] = bv;
          if (!sel) zl[rowl][col] = bv;
        }
  }
  // stage small-GEMM weights (L2-resident, plain vector loads; 1024 threads)
  for (int idx = tid; idx < 160 * 16; idx += 1024) {
    int r = idx >> 4, c8 = (idx & 15) << 3;
    const bf16* src;
    if (r < 128)      src = Wdtb + r * 128;
    else if (r < 144) src = Wbb + (r - 128) * 128;
    else              src = Wcb + (r - 144) * 128;
    *(short8*)&wl[r][c8] = *(const short8*)(src + c8);
  }
  __syncthreads();

  // ----- phase 3: dt/Bv/Cv GEMM (waves 0-3 only) -----
  if (tid < 256) {
    int l = tid & 63, w = tid >> 6;
    int lr = l & 15, lk = (l >> 4) * 8, lj = (l >> 4) * 4;
    f32x4 acc2[10];
#pragma unroll
    for (int n = 0; n < 10; ++n)
#pragma unroll
      for (int j = 0; j < 4; ++j) acc2[n][j] = 0.f;

#pragma unroll
    for (int kk = 0; kk < 128; kk += 32) {
      bf16x8 a = *(const bf16x8*)&zl[w * 16 + lr][kk + lk];
#pragma unroll
      for (int n = 0; n < 10; ++n) {
        bf16x8 bfr = *(const bf16x8*)&wl[n * 16 + lr][kk + lk];
        acc2[n] = __builtin_amdgcn_mfma_f32_16x16x32_bf16(a, bfr, acc2[n], 0, 0, 0);
      }
    }

#pragma unroll
    for (int n = 0; n < 10; ++n) {
      int o = n * 16 + lr;
#pragma unroll
      for (int j = 0; j < 4; ++j) {
        int row = w * 16 + lj + j;          // local row 0..63
        float v = acc2[n][j];
        if (o < 128) {
          v += bdtf[o];
          v = fmaxf(v, 0.f) + log1pf(expf(-fabsf(v)));   // stable softplus
          dt[(size_t)(m0 + row) * SCAN + o] = v;
          dtlb[row][o] = f2bf(v);
        } else if (o < 144) {
          Bv[(size_t)(m0 + row) * STATE + (o - 128)] = v;
          Blcb[row][o - 128] = f2bf(v);
        } else {
          Cv[(size_t)(m0 + row) * STATE + (o - 144)] = v;
        }
      }
    }
  }
  __syncthreads();

  // ----- phase 4: local scan, threads < 512 = (chunk 0..3) x (n 0..127) -----
  if (tid < 512) {
    int n  = tid & 127;
    int cc = tid >> 7;                       // chunk 0..3
    int b   = m0 >> 12;
    int ch0 = (m0 & 4095) >> 4;
    float A[STATE];
#pragma unroll
    for (int k = 0; k < STATE; ++k) A[k] = Aneg[n * STATE + k];

    float st[STATE], ap[STATE];
#pragma unroll
    for (int k = 0; k < STATE; ++k) { st[k] = 0.f; ap[k] = 1.f; }
#pragma unroll
    for (int t = 0; t < LCH; ++t) {
      int row = cc * LCH + t;
      float d = bf2f(dtlb[row][n]);
      float u = d * bf2f(zl[row][n]);
#pragma unroll
      for (int kg = 0; kg < 4; ++kg) {
        unsigned long long bb = *(const unsigned long long*)&Blcb[row][kg * 4];
        float b0 = bfbits((unsigned short)bb);
        float b1 = bfbits((unsigned short)(bb >> 16));
        float b2 = bfbits((unsigned short)(bb >> 32));
        float b3 = bfbits((unsigned short)(bb >> 48));
        float a;
        a = fmaf(d, A[kg*4+0], 1.f); st[kg*4+0] = fmaf(a, st[kg*4+0], u * b0); ap[kg*4+0] *= a;
        a = fmaf(d, A[kg*4+1], 1.f); st[kg*4+1] = fmaf(a, st[kg*4+1], u * b1); ap[kg*4+1] *= a;
        a = fmaf(d, A[kg*4+2], 1.f); st[kg*4+2] = fmaf(a, st[kg*4+2], u * b2); ap[kg*4+2] *= a;
        a = fmaf(d, A[kg*4+3], 1.f); st[kg*4+3] = fmaf(a, st[kg*4+3], u * b3); ap[kg*4+3] *= a;
      }
    }
    size_t base = ((size_t)b * NCH + (ch0 + cc)) * (STATE * SCAN) + n;
#pragma unroll
    for (int k = 0; k < STATE; ++k) {
      fin[base + k * SCAN] = st[k];
      apr[base + k * SCAN] = ap[k];
    }
  }
}

// ---------------------------------------------------------------------------
// K3b: combine across chunks; apr overwritten in place with INCOMING state.
// ---------------------------------------------------------------------------
__global__ __launch_bounds__(64) void k3b(const float* __restrict__ fin,
                                          float* __restrict__ apr) {
  int c  = blockIdx.x * 64 + threadIdx.x;   // 0..8191
  int b  = c >> 11;
  int kn = c & 2047;
  size_t base = (size_t)b * NCH * 2048 + kn;
  float s = 0.f;
  for (int g = 0; g < NCH; g += 16) {
    float fv[16], av[16];
#pragma unroll
    for (int i = 0; i < 16; ++i) {
      size_t o = base + (size_t)(g + i) * 2048;
      fv[i] = fin[o];
      av[i] = apr[o];
    }
#pragma unroll
    for (int i = 0; i < 16; ++i) {
      size_t o = base + (size_t)(g + i) * 2048;
      apr[o] = s;
      s = fmaf(av[i], s, fv[i]);
    }
  }
}

// ---------------------------------------------------------------------------
// K3c: re-scan with incoming state; yg = (sum_k st*C) * gate (bf16).
// yg aliases z (each element read before written by the same thread).
// ---------------------------------------------------------------------------
__global__ __launch_bounds__(128) void k3c(
    const float* __restrict__ dt, const bf16* z,
    const float* __restrict__ Bv, const float* __restrict__ Cv,
    const float* __restrict__ Aneg, const float* __restrict__ inc,
    const bf16* __restrict__ gate, bf16* yg) {
  __shared__ float Bl[LCH][STATE];
  __shared__ float Cl[LCH][STATE];
  int n  = threadIdx.x;
  int ch = blockIdx.x, b = blockIdx.y;
  int t0 = ch * LCH;
  if (n < LCH * STATE / 4)
    ((float4*)&Bl[0][0])[n] = ((const float4*)(Bv + ((size_t)b * SEQ + t0) * STATE))[n];
  else if (n < LCH * STATE / 2)
    ((float4*)&Cl[0][0])[n - LCH * STATE / 4] =
        ((const float4*)(Cv + ((size_t)b * SEQ + t0) * STATE))[n - LCH * STATE / 4];

  size_t base = ((size_t)b * NCH + ch) * (STATE * SCAN) + n;
  float A[STATE], st[STATE];
#pragma unroll
  for (int k = 0; k < STATE; ++k) {
    A[k]  = Aneg[n * STATE + k];
    st[k] = inc[base + k * SCAN];
  }
  __syncthreads();

  const float* dtp = dt   + ((size_t)b * SEQ + t0) * SCAN + n;
  const bf16*  zp  = z    + ((size_t)b * SEQ + t0) * SCAN + n;
  const bf16*  gp  = gate + ((size_t)b * SEQ + t0) * SCAN + n;
  bf16*        yp  = yg   + ((size_t)b * SEQ + t0) * SCAN + n;
#pragma unroll 4
  for (int t = 0; t < LCH; ++t) {
    float d = dtp[t * SCAN];
    float u = d * bf2f(zp[t * SCAN]);
    float g = bf2f(gp[t * SCAN]);
    float y0 = 0.f, y1 = 0.f, y2 = 0.f, y3 = 0.f;
#pragma unroll
    for (int kg = 0; kg < 4; ++kg) {
      float4 B4 = *(const float4*)&Bl[t][kg * 4];
      float4 C4 = *(const float4*)&Cl[t][kg * 4];
      float a, p = 0.f;
      a = fmaf(d, A[kg*4+0], 1.f); st[kg*4+0] = fmaf(a, st[kg*4+0], u * B4.x); p = fmaf(st[kg*4+0], C4.x, p);
      a = fmaf(d, A[kg*4+1], 1.f); st[kg*4+1] = fmaf(a, st[kg*4+1], u * B4.y); p = fmaf(st[kg*4+1], C4.y, p);
      a = fmaf(d, A[kg*4+2], 1.f); st[kg*4+2] = fmaf(a, st[kg*4+2], u * B4.z); p = fmaf(st[kg*4+2], C4.z, p);
      a = fmaf(d, A[kg*4+3], 1.f); st[kg*4+3] = fmaf(a, st[kg*4+3], u * B4.w); p = fmaf(st[kg*4+3], C4.w, p);
      if (kg == 0) y0 = p; else if (kg == 1) y1 = p; else if (kg == 2) y2 = p; else y3 = p;
    }
    float y = (y0 + y1) + (y2 + y3);
    yp[t * SCAN] = f2bf(y * g);
  }
}

// ---------------------------------------------------------------------------
// K4: out = yg @ Wo^T -> [16384,2048]. BM=128, BN=64, K=128 staged whole
// (48 KB, single barrier, XOR-swizzled). grid(128,32), 3 blocks/CU.
// ---------------------------------------------------------------------------
__device__ __forceinline__ int swz256(int row, int colbyte) {
  return row * 256 + (colbyte ^ ((row & 7) << 4));
}

__global__ __launch_bounds__(256) void k4_out(const bf16* __restrict__ yg,
                                              const bf16* __restrict__ Wo,
                                              void* __restrict__ outv,
                                              const int* __restrict__ flag) {
  __shared__ char lds[49152];   // A 32K @0, B 16K @32768
  int tid = threadIdx.x;
  int mb = blockIdx.x, nb = blockIdx.y;
  int w = tid >> 6;

#pragma unroll
  for (int i = 0; i < 8; ++i) {
    int off = i * 4096 + tid * 16;
    int r   = off >> 8;
    int cbl = off & 255;
    int cbs = cbl ^ ((r & 7) << 4);
    const bf16* src = yg + (size_t)(mb * 128 + r) * SCAN + (cbs >> 1);
    __builtin_amdgcn_global_load_lds((const AS1 void*)src,
                                     (AS3 void*)(lds + i * 4096 + w * 1024), 16, 0, 0);
  }
#pragma unroll
  for (int i = 0; i < 4; ++i) {
    int off = i * 4096 + tid * 16;
    int r   = off >> 8;
    int cbl = off & 255;
    int cbs = cbl ^ ((r & 7) << 4);
    const bf16* src = Wo + (size_t)(nb * 64 + r) * SCAN + (cbs >> 1);
    __builtin_amdgcn_global_load_lds((const AS1 void*)src,
                                     (AS3 void*)(lds + 32768 + i * 4096 + w * 1024), 16, 0, 0);
  }
  __syncthreads();

  int l = tid & 63;
  int lr = l & 15, lk = (l >> 4) * 8;
  f32x4 acc[2][4];
#pragma unroll
  for (int m = 0; m < 2; ++m)
#pragma unroll
    for (int n = 0; n < 4; ++n)
#pragma unroll
      for (int j = 0; j < 4; ++j) acc[m][n][j] = 0.f;

#pragma unroll
  for (int kk = 0; kk < 128; kk += 32) {
    int cb = (kk + lk) * 2;
    bf16x8 a[2], b[4];
#pragma unroll
    for (int m = 0; m < 2; ++m)
      a[m] = *(const bf16x8*)(lds + swz256(w * 32 + m * 16 + lr, cb));
#pragma unroll
    for (int n = 0; n < 4; ++n)
      b[n] = *(const bf16x8*)(lds + 32768 + swz256(n * 16 + lr, cb));
#pragma unroll
    for (int m = 0; m < 2; ++m)
#pragma unroll
      for (int n = 0; n < 4; ++n)
        acc[m][n] = __builtin_amdgcn_mfma_f32_16x16x32_bf16(a[m], b[n], acc[m][n], 0, 0, 0);
  }

  int f = *flag;
  int lj = (l >> 4) * 4;
#pragma unroll
  for (int m = 0; m < 2; ++m)
#pragma unroll
    for (int n = 0; n < 4; ++n)
#pragma unroll
      for (int j = 0; j < 4; ++j) {
        int row = mb * 128 + w * 32 + m * 16 + lj + j;
        int col = nb * 64 + n * 16 + lr;
        size_t off = (size_t)row * DIM + col;
        float v = acc[m][n][j];
        if (f) ((bf16*)outv)[off] = f2bf(v);
        else   ((float*)outv)[off] = v;
      }
}

// ---------------------------------------------------------------------------
extern "C" void kernel_launch(void* const* d_in, const int* in_sizes, int n_in,
                              void* d_out, int out_size, void* d_ws, size_t ws_size,
                              hipStream_t stream) {
  const void* x     = d_in[0];
  const void* Wi    = d_in[1];
  const void* Wo    = d_in[2];
  const void* A_log = d_in[3];
  const void* Wb    = d_in[4];
  const void* Wc    = d_in[5];
  const void* Wdt   = d_in[6];
  const void* b_dt  = d_in[7];
  const void* Wg    = d_in[8];

  const size_t M = (size_t)BATCH * SEQ;   // 16384
  char* p = (char*)d_ws;
  int*   flag = (int*)p;    p += 256;
  bf16*  Wzg  = (bf16*)p;   p += (size_t)2 * SCAN * DIM * 2;   // [256][2048]
  bf16*  Wob  = (bf16*)p;   p += (size_t)DIM * SCAN * 2;
  bf16*  Wdtb = (bf16*)p;   p += (size_t)SCAN * SCAN * 2;
  bf16*  Wbb  = (bf16*)p;   p += (size_t)STATE * SCAN * 2;
  bf16*  Wcb  = (bf16*)p;   p += (size_t)STATE * SCAN * 2;
  float* bdtf = (float*)p;  p += SCAN * 4;
  float* Anegf= (float*)p;  p += (size_t)SCAN * STATE * 4;
  bf16*  z    = (bf16*)p;   p += M * SCAN * 2;
  bf16*  gate = (bf16*)p;   p += M * SCAN * 2;
  bf16*  yg   = z;                                   // alias: k3c reads z before writing yg
  float* dt   = (float*)p;  p += M * SCAN * 4;
  float* Bv   = (float*)p;  p += M * STATE * 4;
  float* Cv   = (float*)p;  p += M * STATE * 4;
  float* fin  = (float*)p;  p += (size_t)BATCH * NCH * SCAN * STATE * 4;
  float* apr  = (float*)p;  p += (size_t)BATCH * NCH * SCAN * STATE * 4;   // becomes inc after k3b

  kconv_w <<<256, 256, 0, stream>>>((const unsigned short*)x,
                                    Wi, Wg, Wo, Wdt, Wb, Wc, b_dt, A_log,
                                    Wzg, Wob, Wdtb, Wbb, Wcb, bdtf, Anegf, flag);
  k12_zg  <<<dim3(256), 1024, 0, stream>>>(x, Wzg, Wdtb, Wbb, Wcb, bdtf, Anegf,
                                           z, gate, dt, Bv, Cv, fin, apr, flag);
  k3b     <<<dim3(128), 64, 0, stream>>>(fin, apr);
  k3c     <<<dim3(NCH, BATCH), 128, 0, stream>>>(dt, z, Bv, Cv, Anegf, apr, gate, yg);
  k4_out  <<<dim3(128, 32), 256, 0, stream>>>(yg, Wob, d_out, flag);
}